// Round 1
// baseline (383.186 us; speedup 1.0000x reference)
//
#include <hip/hip_runtime.h>

typedef unsigned int uint32;
typedef unsigned short u16;
typedef __attribute__((ext_vector_type(8))) short short8;
typedef __attribute__((ext_vector_type(4))) float f32x4;

#define NG 1024

__device__ __forceinline__ u16 f2bf(float f) {
  uint32 u = __builtin_bit_cast(uint32, f);
  u += 0x7fffu + ((u >> 16) & 1u);   // round-to-nearest-even
  return (u16)(u >> 16);
}
__device__ __forceinline__ float bf2f(u16 h) {
  uint32 u = ((uint32)h) << 16;
  return __builtin_bit_cast(float, u);
}

// ---------------- sigma = mu + eps*exp(logstd), fp32 exact ----------------
__global__ __launch_bounds__(256) void k_sigma(const float* __restrict__ mu,
                                               const float* __restrict__ ls,
                                               const float* __restrict__ ep,
                                               float* __restrict__ sig) {
  size_t i = ((size_t)blockIdx.x * 256 + threadIdx.x) * 4;
  float4 m = *(const float4*)(mu + i);
  float4 l = *(const float4*)(ls + i);
  float4 e = *(const float4*)(ep + i);
  float4 s;
  s.x = m.x + e.x * expf(l.x);
  s.y = m.y + e.y * expf(l.y);
  s.z = m.z + e.z * expf(l.z);
  s.w = m.w + e.w * expf(l.w);
  *(float4*)(sig + i) = s;
}

// ---------------- M = bf16(A^T), MT = bf16(A), P = bf16(I + A^T) ----------------
__global__ __launch_bounds__(256) void k_init(const float* __restrict__ A,
                                              u16* __restrict__ M,
                                              u16* __restrict__ MT,
                                              u16* __restrict__ P) {
  __shared__ float tile[64][65];
  const int bi = blockIdx.x & 15;
  const int bj = blockIdx.x >> 4;
  const int i0 = bi * 64, j0 = bj * 64;
  const int t = threadIdx.x;
  const int rl = t >> 2;
  const int q = t & 3;
#pragma unroll
  for (int s = 0; s < 4; ++s) {
    int c4 = (q + s * 4) * 4;
    float4 v = *(const float4*)&A[(size_t)(j0 + rl) * NG + i0 + c4];
    tile[rl][c4 + 0] = v.x;
    tile[rl][c4 + 1] = v.y;
    tile[rl][c4 + 2] = v.z;
    tile[rl][c4 + 3] = v.w;
    u16 h0 = f2bf(v.x), h1 = f2bf(v.y), h2 = f2bf(v.z), h3 = f2bf(v.w);
    uint2 pk;
    pk.x = (uint32)h0 | ((uint32)h1 << 16);
    pk.y = (uint32)h2 | ((uint32)h3 << 16);
    *(uint2*)&MT[(size_t)(j0 + rl) * NG + i0 + c4] = pk;   // MT = (A^T)^T = A
  }
  __syncthreads();
#pragma unroll
  for (int s = 0; s < 4; ++s) {
    int c4 = (q + s * 4) * 4;
    int gi = i0 + rl;
    u16 mh[4], ph[4];
#pragma unroll
    for (int u = 0; u < 4; ++u) {
      float f = tile[c4 + u][rl];                 // = A[j0+c4+u][i0+rl] = M[gi][j0+c4+u]
      mh[u] = f2bf(f);
      float pf = f + ((gi == (j0 + c4 + u)) ? 1.0f : 0.0f);
      ph[u] = f2bf(pf);
    }
    uint2 mk, pkk;
    mk.x = (uint32)mh[0] | ((uint32)mh[1] << 16);
    mk.y = (uint32)mh[2] | ((uint32)mh[3] << 16);
    pkk.x = (uint32)ph[0] | ((uint32)ph[1] << 16);
    pkk.y = (uint32)ph[2] | ((uint32)ph[3] << 16);
    *(uint2*)&M[(size_t)gi * NG + j0 + c4] = mk;
    *(uint2*)&P[(size_t)gi * NG + j0 + c4] = pkk;
  }
}

// ---------------- C = A@B (+Cadd), bf16 in/out, optional C^T output ----------------
// B is passed in TRANSPOSED layout BT[n][k] so staging is coalesced + b128-friendly.
__global__ __launch_bounds__(512) void k_mm(const u16* __restrict__ A,
                                            const u16* __restrict__ BT,
                                            const u16* __restrict__ Cadd,
                                            u16* __restrict__ C,
                                            u16* __restrict__ CT) {
  __shared__ __align__(16) u16 At[64][72];
  __shared__ __align__(16) u16 Bt[64][72];
  const int t = threadIdx.x;
  const int bm = (blockIdx.x & 15) * 64;
  const int bn = (blockIdx.x >> 4) * 64;
  const int r = t >> 3;
  const int c8 = (t & 7) * 8;
  const int w = t >> 6;
  const int lane = t & 63;
  const int quad = lane >> 4;
  const int l15 = lane & 15;
  const int m0w = (w & 3) * 16;   // 16-row strip per wave
  const int n0w = (w >> 2) * 32;  // 32-col strip per wave

  f32x4 acc[2];
  acc[0] = (f32x4){0.f, 0.f, 0.f, 0.f};
  acc[1] = (f32x4){0.f, 0.f, 0.f, 0.f};

  for (int kb = 0; kb < 16; ++kb) {
    int k0 = kb * 64;
    uint4 av = *(const uint4*)&A[(size_t)(bm + r) * NG + k0 + c8];
    uint4 bv = *(const uint4*)&BT[(size_t)(bn + r) * NG + k0 + c8];
    __syncthreads();
    *(uint4*)&At[r][c8] = av;
    *(uint4*)&Bt[r][c8] = bv;
    __syncthreads();
#pragma unroll
    for (int ks = 0; ks < 2; ++ks) {
      int kk = ks * 32 + quad * 8;
      short8 af = __builtin_bit_cast(short8, *(const uint4*)&At[m0w + l15][kk]);
      short8 b0 = __builtin_bit_cast(short8, *(const uint4*)&Bt[n0w + l15][kk]);
      short8 b1 = __builtin_bit_cast(short8, *(const uint4*)&Bt[n0w + 16 + l15][kk]);
      acc[0] = __builtin_amdgcn_mfma_f32_16x16x32_bf16(af, b0, acc[0], 0, 0, 0);
      acc[1] = __builtin_amdgcn_mfma_f32_16x16x32_bf16(af, b1, acc[1], 0, 0, 0);
    }
  }

#pragma unroll
  for (int cb = 0; cb < 2; ++cb) {
    int gcol = bn + n0w + cb * 16 + l15;
    int grow = bm + m0w + quad * 4;
    f32x4 v = acc[cb];
    u16 h[4];
#pragma unroll
    for (int rr = 0; rr < 4; ++rr) {
      float f = v[rr];
      if (Cadd) f += bf2f(Cadd[(size_t)(grow + rr) * NG + gcol]);
      h[rr] = f2bf(f);
      C[(size_t)(grow + rr) * NG + gcol] = h[rr];
    }
    if (CT) {
      uint2 pk;
      pk.x = (uint32)h[0] | ((uint32)h[1] << 16);
      pk.y = (uint32)h[2] | ((uint32)h[3] << 16);
      *(uint2*)&CT[(size_t)gcol * NG + grow] = pk;   // 8B packed transposed store
    }
  }
}

// ---------------- z_b = W[idx_b, idx_b] @ sig_b  (fused gather + bmm) ----------------
__global__ __launch_bounds__(256) void k_bmm(const u16* __restrict__ W,
                                             const float* __restrict__ sig,
                                             const int* __restrict__ nidx,
                                             float* __restrict__ z) {
  __shared__ __align__(16) u16 s_sub[128][136];
  __shared__ __align__(16) u16 s_sigT[64][136];
  __shared__ __align__(16) u16 s_row[4][1024];
  __shared__ int s_idx[128];

  const int b = blockIdx.x;
  const int t = threadIdx.x;
  const int w = t >> 6;
  const int lane = t & 63;

  if (t < 128) s_idx[t] = nidx[b * 128 + t];

  // stage sig^T in bf16 (coalesced fp32 reads, scattered LDS b16 writes)
  {
    const float4* sp = (const float4*)(sig + (size_t)b * 8192);
#pragma unroll
    for (int q = 0; q < 8; ++q) {
      int f = t + q * 256;
      float4 v = sp[f];
      int base = f * 4;
      int j = base >> 6;    // row within batch (k index)
      int d0 = base & 63;   // col (n index)
      s_sigT[d0 + 0][j] = f2bf(v.x);
      s_sigT[d0 + 1][j] = f2bf(v.y);
      s_sigT[d0 + 2][j] = f2bf(v.z);
      s_sigT[d0 + 3][j] = f2bf(v.w);
    }
  }
  __syncthreads();

  // gather sub = W[idx,idx]: wave w owns rows i = w + 4*it; coalesced full-row
  // loads into per-wave row buffer, then LDS column gather. 2-stage pipeline.
  {
    const int gc0 = s_idx[lane];
    const int gc1 = s_idx[64 + lane];
    const uint4* wm = (const uint4*)W;   // 128 uint4 per 1024-elem row
    int r0 = s_idx[w];
    uint4 v0 = wm[(size_t)r0 * 128 + lane * 2];
    uint4 v1 = wm[(size_t)r0 * 128 + lane * 2 + 1];
    for (int it = 0; it < 32; ++it) {
      int i = w + it * 4;
      uint4 c0 = v0, c1 = v1;
      if (it < 31) {
        int rn = s_idx[w + (it + 1) * 4];
        v0 = wm[(size_t)rn * 128 + lane * 2];
        v1 = wm[(size_t)rn * 128 + lane * 2 + 1];
      }
      uint4* rb = (uint4*)&s_row[w][0];
      rb[lane * 2] = c0;
      rb[lane * 2 + 1] = c1;
      // same-wave DS ops are in-order: read-after-write within wave is safe
      s_sub[i][lane] = s_row[w][gc0];
      s_sub[i][64 + lane] = s_row[w][gc1];
    }
  }
  __syncthreads();

  const int quad = lane >> 4;
  const int l15 = lane & 15;
  f32x4 acc[2][4];
#pragma unroll
  for (int a = 0; a < 2; ++a)
#pragma unroll
    for (int c = 0; c < 4; ++c) acc[a][c] = (f32x4){0.f, 0.f, 0.f, 0.f};

#pragma unroll
  for (int kt = 0; kt < 4; ++kt) {
    int kk = kt * 32 + quad * 8;
    short8 a0 = __builtin_bit_cast(short8, *(const uint4*)&s_sub[w * 32 + l15][kk]);
    short8 a1 = __builtin_bit_cast(short8, *(const uint4*)&s_sub[w * 32 + 16 + l15][kk]);
#pragma unroll
    for (int ct = 0; ct < 4; ++ct) {
      short8 bf = __builtin_bit_cast(short8, *(const uint4*)&s_sigT[ct * 16 + l15][kk]);
      acc[0][ct] = __builtin_amdgcn_mfma_f32_16x16x32_bf16(a0, bf, acc[0][ct], 0, 0, 0);
      acc[1][ct] = __builtin_amdgcn_mfma_f32_16x16x32_bf16(a1, bf, acc[1][ct], 0, 0, 0);
    }
  }

#pragma unroll
  for (int rt = 0; rt < 2; ++rt) {
    int gr0 = b * 128 + w * 32 + rt * 16 + quad * 4;
#pragma unroll
    for (int ct = 0; ct < 4; ++ct) {
      int col = ct * 16 + l15;
#pragma unroll
      for (int r = 0; r < 4; ++r) {
        z[(size_t)(gr0 + r) * 64 + col] = acc[rt][ct][r];
      }
    }
  }
}

extern "C" void kernel_launch(void* const* d_in, const int* in_sizes, int n_in,
                              void* d_out, int out_size, void* d_ws, size_t ws_size,
                              hipStream_t stream) {
  const float* A  = (const float*)d_in[0];
  const float* mu = (const float*)d_in[1];
  const float* ls = (const float*)d_in[2];
  const float* ep = (const float*)d_in[3];
  const int* nidx = (const int*)d_in[4];

  float* sig = (float*)d_out;                 // 16777216 floats
  float* z   = sig + (size_t)16777216;        // 16777216 floats

  u16* base = (u16*)d_ws;                     // needs 16 MB of ws
  const size_t MM = (size_t)NG * NG;
  u16* M    = base + 0 * MM;
  u16* MTm  = base + 1 * MM;
  u16* Msq  = base + 2 * MM;
  u16* MsqT = base + 3 * MM;
  u16* M4   = base + 4 * MM;
  u16* M4T  = base + 5 * MM;
  u16* P    = base + 6 * MM;
  u16* Pt   = base + 7 * MM;

  k_sigma<<<16384, 256, 0, stream>>>(mu, ls, ep, sig);
  k_init<<<256, 256, 0, stream>>>(A, M, MTm, P);
  // W = (I - A^T)^{-1} ~= (I+M)(I+M^2)(I+M^4)(I+M^8), M = A^T  (err ~0.32^16)
  k_mm<<<256, 512, 0, stream>>>(M, MTm, nullptr, Msq, MsqT);     // M^2 (+T)
  k_mm<<<256, 512, 0, stream>>>(P, MsqT, P, Pt, nullptr);        // Sum_{k<4}
  k_mm<<<256, 512, 0, stream>>>(Msq, MsqT, nullptr, M4, M4T);    // M^4 (+T)
  k_mm<<<256, 512, 0, stream>>>(Pt, M4T, Pt, P, nullptr);        // Sum_{k<8}
  k_mm<<<256, 512, 0, stream>>>(M4, M4T, nullptr, Msq, MsqT);    // M^8 (+T)
  k_mm<<<256, 512, 0, stream>>>(P, MsqT, P, Pt, nullptr);        // Sum_{k<16} = W
  k_bmm<<<2048, 256, 0, stream>>>(Pt, sig, nidx, z);
}

// Round 3
// 336.292 us; speedup vs baseline: 1.1394x; 1.1394x over previous
//
#include <hip/hip_runtime.h>

typedef unsigned int uint32;
typedef unsigned short u16;
typedef __attribute__((ext_vector_type(8))) short short8;
typedef __attribute__((ext_vector_type(4))) float f32x4;

#define NG 1024

__device__ __forceinline__ u16 f2bf(float f) {
  uint32 u = __builtin_bit_cast(uint32, f);
  u += 0x7fffu + ((u >> 16) & 1u);   // round-to-nearest-even
  return (u16)(u >> 16);
}
__device__ __forceinline__ float bf2f(u16 h) {
  uint32 u = ((uint32)h) << 16;
  return __builtin_bit_cast(float, u);
}

// ---- fused: blocks [0,256): M=bf16(A^T), MT=bf16(A), P=bf16(I+A^T)
//             blocks [256,4352): sigma = mu + eps*exp(logstd), 16 elem/thread ----
__global__ __launch_bounds__(256) void k_pre(const float* __restrict__ A,
                                             const float* __restrict__ mu,
                                             const float* __restrict__ ls,
                                             const float* __restrict__ ep,
                                             float* __restrict__ sig,
                                             u16* __restrict__ M,
                                             u16* __restrict__ MT,
                                             u16* __restrict__ P) {
  __shared__ float tile[64][65];
  const int t = threadIdx.x;
  if (blockIdx.x >= 256) {
    // ---- sigma: 4096 blocks x 4096 elems ----
    size_t base = (size_t)(blockIdx.x - 256) * 4096 + t * 4;
#pragma unroll
    for (int j = 0; j < 4; ++j) {
      size_t i = base + (size_t)j * 1024;
      f32x4 m = __builtin_nontemporal_load((const f32x4*)(mu + i));
      f32x4 l = __builtin_nontemporal_load((const f32x4*)(ls + i));
      f32x4 e = __builtin_nontemporal_load((const f32x4*)(ep + i));
      f32x4 s;
      s.x = m.x + e.x * expf(l.x);
      s.y = m.y + e.y * expf(l.y);
      s.z = m.z + e.z * expf(l.z);
      s.w = m.w + e.w * expf(l.w);
      *(f32x4*)(sig + i) = s;   // regular store: k_bmm re-reads sig (LLC)
    }
    return;
  }
  // ---- init ----
  const int bi = blockIdx.x & 15;
  const int bj = blockIdx.x >> 4;
  const int i0 = bi * 64, j0 = bj * 64;
  const int rl = t >> 2;
  const int q = t & 3;
#pragma unroll
  for (int s = 0; s < 4; ++s) {
    int c4 = (q + s * 4) * 4;
    float4 v = *(const float4*)&A[(size_t)(j0 + rl) * NG + i0 + c4];
    tile[rl][c4 + 0] = v.x;
    tile[rl][c4 + 1] = v.y;
    tile[rl][c4 + 2] = v.z;
    tile[rl][c4 + 3] = v.w;
    u16 h0 = f2bf(v.x), h1 = f2bf(v.y), h2 = f2bf(v.z), h3 = f2bf(v.w);
    uint2 pk;
    pk.x = (uint32)h0 | ((uint32)h1 << 16);
    pk.y = (uint32)h2 | ((uint32)h3 << 16);
    *(uint2*)&MT[(size_t)(j0 + rl) * NG + i0 + c4] = pk;   // MT = (A^T)^T = A
  }
  __syncthreads();
#pragma unroll
  for (int s = 0; s < 4; ++s) {
    int c4 = (q + s * 4) * 4;
    int gi = i0 + rl;
    u16 mh[4], ph[4];
#pragma unroll
    for (int u = 0; u < 4; ++u) {
      float f = tile[c4 + u][rl];                 // = M[gi][j0+c4+u]
      mh[u] = f2bf(f);
      float pf = f + ((gi == (j0 + c4 + u)) ? 1.0f : 0.0f);
      ph[u] = f2bf(pf);
    }
    uint2 mk, pkk;
    mk.x = (uint32)mh[0] | ((uint32)mh[1] << 16);
    mk.y = (uint32)mh[2] | ((uint32)mh[3] << 16);
    pkk.x = (uint32)ph[0] | ((uint32)ph[1] << 16);
    pkk.y = (uint32)ph[2] | ((uint32)ph[3] << 16);
    *(uint2*)&M[(size_t)gi * NG + j0 + c4] = mk;
    *(uint2*)&P[(size_t)gi * NG + j0 + c4] = pkk;
  }
}

// ---------------- C = A@B, bf16; B passed TRANSPOSED (BT[n][k]).
// Outputs (each nullable): C (row-major), CT (C^T), CTI (I + C^T). ----------------
__device__ __forceinline__ void mm_body(const u16* __restrict__ A,
                                        const u16* __restrict__ BT,
                                        u16* __restrict__ C,
                                        u16* __restrict__ CT,
                                        u16* __restrict__ CTI,
                                        int bid) {
  __shared__ __align__(16) u16 At[64][72];
  __shared__ __align__(16) u16 Bt[64][72];
  const int t = threadIdx.x;
  const int bm = (bid & 15) * 64;
  const int bn = (bid >> 4) * 64;
  const int r = t >> 3;
  const int c8 = (t & 7) * 8;
  const int w = t >> 6;
  const int lane = t & 63;
  const int quad = lane >> 4;
  const int l15 = lane & 15;
  const int m0w = (w & 3) * 16;   // 16-row strip per wave
  const int n0w = (w >> 2) * 32;  // 32-col strip per wave

  f32x4 acc[2];
  acc[0] = (f32x4){0.f, 0.f, 0.f, 0.f};
  acc[1] = (f32x4){0.f, 0.f, 0.f, 0.f};

  for (int kb = 0; kb < 16; ++kb) {
    int k0 = kb * 64;
    uint4 av = *(const uint4*)&A[(size_t)(bm + r) * NG + k0 + c8];
    uint4 bv = *(const uint4*)&BT[(size_t)(bn + r) * NG + k0 + c8];
    __syncthreads();
    *(uint4*)&At[r][c8] = av;
    *(uint4*)&Bt[r][c8] = bv;
    __syncthreads();
#pragma unroll
    for (int ks = 0; ks < 2; ++ks) {
      int kk = ks * 32 + quad * 8;
      short8 af = __builtin_bit_cast(short8, *(const uint4*)&At[m0w + l15][kk]);
      short8 b0 = __builtin_bit_cast(short8, *(const uint4*)&Bt[n0w + l15][kk]);
      short8 b1 = __builtin_bit_cast(short8, *(const uint4*)&Bt[n0w + 16 + l15][kk]);
      acc[0] = __builtin_amdgcn_mfma_f32_16x16x32_bf16(af, b0, acc[0], 0, 0, 0);
      acc[1] = __builtin_amdgcn_mfma_f32_16x16x32_bf16(af, b1, acc[1], 0, 0, 0);
    }
  }

#pragma unroll
  for (int cb = 0; cb < 2; ++cb) {
    int gcol = bn + n0w + cb * 16 + l15;
    int grow = bm + m0w + quad * 4;
    f32x4 v = acc[cb];
    u16 h[4], hI[4];
#pragma unroll
    for (int rr = 0; rr < 4; ++rr) {
      float f = v[rr];
      h[rr] = f2bf(f);
      hI[rr] = f2bf(f + ((gcol == grow + rr) ? 1.0f : 0.0f));
    }
    if (C) {
#pragma unroll
      for (int rr = 0; rr < 4; ++rr) C[(size_t)(grow + rr) * NG + gcol] = h[rr];
    }
    if (CT) {
      uint2 pk;
      pk.x = (uint32)h[0] | ((uint32)h[1] << 16);
      pk.y = (uint32)h[2] | ((uint32)h[3] << 16);
      *(uint2*)&CT[(size_t)gcol * NG + grow] = pk;
    }
    if (CTI) {
      uint2 pk;
      pk.x = (uint32)hI[0] | ((uint32)hI[1] << 16);
      pk.y = (uint32)hI[2] | ((uint32)hI[3] << 16);
      *(uint2*)&CTI[(size_t)gcol * NG + grow] = pk;
    }
  }
}

__global__ __launch_bounds__(512) void k_mm1(const u16* __restrict__ A,
                                             const u16* __restrict__ BT,
                                             u16* __restrict__ C,
                                             u16* __restrict__ CT,
                                             u16* __restrict__ CTI) {
  mm_body(A, BT, C, CT, CTI, blockIdx.x);
}

// two independent matmuls in one launch (2 blocks/CU)
__global__ __launch_bounds__(512) void k_mm_dual(const u16* __restrict__ A0,
                                                 const u16* __restrict__ BT0,
                                                 u16* __restrict__ CTI0,
                                                 const u16* __restrict__ A1,
                                                 const u16* __restrict__ BT1,
                                                 u16* __restrict__ C1) {
  if (blockIdx.x < 256)
    mm_body(A0, BT0, nullptr, nullptr, CTI0, blockIdx.x);
  else
    mm_body(A1, BT1, C1, nullptr, nullptr, blockIdx.x - 256);
}

__global__ __launch_bounds__(512) void k_mm3(const u16* __restrict__ A,
                                             const u16* __restrict__ BT,
                                             u16* __restrict__ C) {
  mm_body(A, BT, C, nullptr, nullptr, blockIdx.x);
}

// ---------------- z_b = W[idx_b, idx_b] @ sig_b  (fused gather + bmm) ----------------
__global__ __launch_bounds__(256) void k_bmm(const u16* __restrict__ W,
                                             const float* __restrict__ sig,
                                             const int* __restrict__ nidx,
                                             float* __restrict__ z) {
  __shared__ __align__(16) u16 s_sub[128][136];
  __shared__ __align__(16) u16 s_sigT[64][136];
  __shared__ __align__(16) u16 s_row[4][1024];
  __shared__ int s_idx[128];

  const int b = blockIdx.x;
  const int t = threadIdx.x;
  const int w = t >> 6;
  const int lane = t & 63;

  if (t < 128) s_idx[t] = nidx[b * 128 + t];

  {
    const float4* sp = (const float4*)(sig + (size_t)b * 8192);
#pragma unroll
    for (int q = 0; q < 8; ++q) {
      int f = t + q * 256;
      float4 v = sp[f];
      int base = f * 4;
      int j = base >> 6;    // row within batch (k index)
      int d0 = base & 63;   // col (n index)
      s_sigT[d0 + 0][j] = f2bf(v.x);
      s_sigT[d0 + 1][j] = f2bf(v.y);
      s_sigT[d0 + 2][j] = f2bf(v.z);
      s_sigT[d0 + 3][j] = f2bf(v.w);
    }
  }
  __syncthreads();

  {
    const int gc0 = s_idx[lane];
    const int gc1 = s_idx[64 + lane];
    const uint4* wm = (const uint4*)W;   // 128 uint4 per 1024-elem row
    int r0 = s_idx[w];
    uint4 v0 = wm[(size_t)r0 * 128 + lane * 2];
    uint4 v1 = wm[(size_t)r0 * 128 + lane * 2 + 1];
    for (int it = 0; it < 32; ++it) {
      int i = w + it * 4;
      uint4 c0 = v0, c1 = v1;
      if (it < 31) {
        int rn = s_idx[w + (it + 1) * 4];
        v0 = wm[(size_t)rn * 128 + lane * 2];
        v1 = wm[(size_t)rn * 128 + lane * 2 + 1];
      }
      uint4* rb = (uint4*)&s_row[w][0];
      rb[lane * 2] = c0;
      rb[lane * 2 + 1] = c1;
      // same-wave DS ops are in-order: read-after-write within wave is safe
      s_sub[i][lane] = s_row[w][gc0];
      s_sub[i][64 + lane] = s_row[w][gc1];
    }
  }
  __syncthreads();

  const int quad = lane >> 4;
  const int l15 = lane & 15;
  f32x4 acc[2][4];
#pragma unroll
  for (int a = 0; a < 2; ++a)
#pragma unroll
    for (int c = 0; c < 4; ++c) acc[a][c] = (f32x4){0.f, 0.f, 0.f, 0.f};

#pragma unroll
  for (int kt = 0; kt < 4; ++kt) {
    int kk = kt * 32 + quad * 8;
    short8 a0 = __builtin_bit_cast(short8, *(const uint4*)&s_sub[w * 32 + l15][kk]);
    short8 a1 = __builtin_bit_cast(short8, *(const uint4*)&s_sub[w * 32 + 16 + l15][kk]);
#pragma unroll
    for (int ct = 0; ct < 4; ++ct) {
      short8 bf = __builtin_bit_cast(short8, *(const uint4*)&s_sigT[ct * 16 + l15][kk]);
      acc[0][ct] = __builtin_amdgcn_mfma_f32_16x16x32_bf16(a0, bf, acc[0][ct], 0, 0, 0);
      acc[1][ct] = __builtin_amdgcn_mfma_f32_16x16x32_bf16(a1, bf, acc[1][ct], 0, 0, 0);
    }
  }

#pragma unroll
  for (int rt = 0; rt < 2; ++rt) {
    int gr0 = b * 128 + w * 32 + rt * 16 + quad * 4;
#pragma unroll
    for (int ct = 0; ct < 4; ++ct) {
      int col = ct * 16 + l15;
#pragma unroll
      for (int r = 0; r < 4; ++r) {
        z[(size_t)(gr0 + r) * 64 + col] = acc[rt][ct][r];
      }
    }
  }
}

extern "C" void kernel_launch(void* const* d_in, const int* in_sizes, int n_in,
                              void* d_out, int out_size, void* d_ws, size_t ws_size,
                              hipStream_t stream) {
  const float* A  = (const float*)d_in[0];
  const float* mu = (const float*)d_in[1];
  const float* ls = (const float*)d_in[2];
  const float* ep = (const float*)d_in[3];
  const int* nidx = (const int*)d_in[4];

  float* sig = (float*)d_out;                 // 16777216 floats
  float* z   = sig + (size_t)16777216;        // 16777216 floats

  u16* base = (u16*)d_ws;                     // 16 MB of ws
  const size_t MM = (size_t)NG * NG;
  u16* M      = base + 0 * MM;
  u16* MT     = base + 1 * MM;
  u16* P      = base + 2 * MM;
  u16* Msq    = base + 3 * MM;
  u16* MsqT   = base + 4 * MM;
  u16* MsqTI  = base + 5 * MM;
  u16* M4TI   = base + 6 * MM;
  u16* B2     = base + 7 * MM;
  u16* W      = Msq;                          // reuse: Msq dead after dual

  // sigma + init fused
  k_pre<<<4352, 256, 0, stream>>>(A, mu, ls, ep, sig, M, MT, P);
  // W = (I - A^T)^{-1} ~= (I+M)(I+M^2)(I+M^4), M = A^T  (err ~0.32^8 ~ 1e-4)
  k_mm1<<<256, 512, 0, stream>>>(M, MT, Msq, MsqT, MsqTI);          // M^2, M^2T, I+M^2T
  k_mm_dual<<<512, 512, 0, stream>>>(Msq, MsqT, M4TI,               // (I+M^4)^T
                                     P, MsqTI, B2);                 // B2=(I+M)(I+M^2)
  k_mm3<<<256, 512, 0, stream>>>(B2, M4TI, W);                      // W = B2(I+M^4)
  k_bmm<<<2048, 256, 0, stream>>>(W, sig, nidx, z);
}